// Round 2
// baseline (1837.391 us; speedup 1.0000x reference)
//
#include <hip/hip_runtime.h>

// 8 independent LSTMs (HID=512, input=1 scalar/step) x T=256, batch 128, then a
// tiny (B,T)->(B,8) projection.
//
// Round 11: W in registers — delete the LDS level from the MFMA path.
//  r10 post-mortem: SQ_LDS_BANK_CONFLICT doubled (1.34e8) because the 8-tile x
//  1-batch-frag wave shape has zero W-fragment reuse: 512 ds_read_b128/CU/step
//  x ~12cyc = 2.56us of the 5.92us step is pure LDS bandwidth. MfmaUtil 15%
//  (MFMA needs only 620cyc/SIMD/step).
//  Changes:
//   - Wave grid 2x2: wave = 16 h-cols (4 gate-tiles) x 32 batch (2 frags).
//     W per wave = 64 bf16x8 frags = 256 VGPR -> loaded ONCE into registers at
//     init (overlaps the verdict wait). Steady loop: ZERO LDS reads for W.
//     Each W frag feeds 2 MFMAs (batch pair) like r9.
//   - h loads: 2-buffer rolling pipeline (8-load chunks), vmcnt-laddered.
//   - Wih/bias -> 1KB LDS broadcast table (keeps VGPR ~400 < 450 spill line).
//   - Exchange protocol identical to r10 (atomic flags at L2 + sc1 escrow,
//     LDS sentinel, INVL1 before h loads; impure fallback = r3 MALL protocol).

#define NBR   8
#define BATCH 128
#define HIDN  512
#define TLEN  256

typedef __attribute__((ext_vector_type(8))) short bf16x8;
typedef __attribute__((ext_vector_type(4))) float f32x4;

__device__ __forceinline__ unsigned short bf16_rne(float f) {
  unsigned int u = __float_as_uint(f);
  u += 0x7FFFu + ((u >> 16) & 1u);
  return (unsigned short)(u >> 16);
}

__device__ __forceinline__ float sigm(float x) {
  return __builtin_amdgcn_rcpf(1.0f + __expf(-x));
}
__device__ __forceinline__ float tanh_(float x) {
  float ax = fabsf(x);
  float e  = __expf(-2.0f * ax);
  float t  = (1.0f - e) * __builtin_amdgcn_rcpf(1.0f + e);
  return copysignf(t, x);
}

#define HLOADX(d, p, OFF, SC) \
  asm volatile("global_load_dwordx4 %0, %1, off offset:" OFF " " SC \
               : "=v"(d) : "v"(p))
#define DLOADX(d, p, SC) \
  asm volatile("global_load_dword %0, %1, off " SC : "=v"(d) : "v"(p))
#define DLOADF(d, p, SC) \
  asm volatile("global_load_dword %0, %1, off " SC : "=v"(d) : "v"(p))
#define QSTOREX(p, v, SC) \
  asm volatile("global_store_dwordx2 %0, %1, off " SC \
               :: "v"(p), "v"(v) : "memory")
#define QSTOREXO(p, v, OFF, SC) \
  asm volatile("global_store_dwordx2 %0, %1, off offset:" OFF " " SC \
               :: "v"(p), "v"(v) : "memory")
#define DSTOREX(p, v, SC) \
  asm volatile("global_store_dword %0, %1, off " SC \
               :: "v"(p), "v"(v) : "memory")
#define WAITV(N) asm volatile("s_waitcnt vmcnt(" #N ")" ::: "memory")
#define INVL1() asm volatile("buffer_inv sc0" ::: "memory")
#define SCHEDB() __builtin_amdgcn_sched_barrier(0)
// L2-executed atomics: cannot be served stale by L1. sc0 on the RET form is
// required (return-old); plain NR form executes at L2, sc1 form at MALL.
#define AUMAX_NR(p, v, SC) \
  asm volatile("global_atomic_umax %0, %1, off " SC :: "v"(p), "v"(v) : "memory")
#define AUMAX_RET(d, p, v, SC) \
  asm volatile("global_atomic_umax %0, %1, %2, off " SC \
               : "=v"(d) : "v"(p), "v"(v) : "memory")

// 8 x 16B: rows bb0/bb1, k-bytes k4*64 within the chunk (chunk base on P).
#define CHUNK_LOAD(BUF, P0, P1, SC) do {      \
    HLOADX((BUF)[0], (P0), "0",   SC);        \
    HLOADX((BUF)[1], (P1), "0",   SC);        \
    HLOADX((BUF)[2], (P0), "64",  SC);        \
    HLOADX((BUF)[3], (P1), "64",  SC);        \
    HLOADX((BUF)[4], (P0), "128", SC);        \
    HLOADX((BUF)[5], (P1), "128", SC);        \
    HLOADX((BUF)[6], (P0), "192", SC);        \
    HLOADX((BUF)[7], (P1), "192", SC);        \
  } while (0)

// 4 ksteps x 4 gates x 2 batch-frags; W from registers, reused across nt.
#define MFMA_CHUNK(C, H) do {                                                 \
    _Pragma("unroll")                                                         \
    for (int k4 = 0; k4 < 4; ++k4) {                                          \
      _Pragma("unroll")                                                       \
      for (int tp = 0; tp < 4; ++tp) {                                        \
        bf16x8 wf = __builtin_bit_cast(bf16x8, wreg[tp * 16 + 4 * (C) + k4]); \
        acc[tp][0] = __builtin_amdgcn_mfma_f32_16x16x32_bf16(                 \
            wf, __builtin_bit_cast(bf16x8, (H)[2 * k4 + 0]), acc[tp][0], 0, 0, 0); \
        acc[tp][1] = __builtin_amdgcn_mfma_f32_16x16x32_bf16(                 \
            wf, __builtin_bit_cast(bf16x8, (H)[2 * k4 + 1]), acc[tp][1], 0, 0, 0); \
      }                                                                       \
    }                                                                         \
  } while (0)

// FM==1: pure (plain h exchange in local L2, atomic flags, LDS sentinel).
// FM==0: r3 MALL protocol (sc0 sc1 everywhere).
#define STEP_LOOP(SC, FM)                                                     \
  for (int t = 0; t < TLEN; ++t) {                                            \
    f32x4 acc[4][2];                                                          \
    _Pragma("unroll")                                                         \
    for (int tp = 0; tp < 4; ++tp)                                            \
      { acc[tp][0] = (f32x4){0.f,0.f,0.f,0.f}; acc[tp][1] = (f32x4){0.f,0.f,0.f,0.f}; } \
    const char* pc0 = curB + hoff0;                                           \
    const char* pc1 = curB + hoff1;                                           \
    uint4 hA[8], hB[8];                                                       \
    float cv0, cv1;                                                           \
    DLOADF(cv0, c0p + t, "");                                                 \
    DLOADF(cv1, c1p + t, "");                                                 \
    CHUNK_LOAD(hA, pc0,       pc1,       SC);                                 \
    CHUNK_LOAD(hB, pc0 + 256, pc1 + 256, SC);                                 \
    WAITV(8); SCHEDB(); MFMA_CHUNK(0, hA);                                    \
    CHUNK_LOAD(hA, pc0 + 512, pc1 + 512, SC);                                 \
    WAITV(8); SCHEDB(); MFMA_CHUNK(1, hB);                                    \
    CHUNK_LOAD(hB, pc0 + 768, pc1 + 768, SC);                                 \
    WAITV(8); SCHEDB(); MFMA_CHUNK(2, hA);                                    \
    WAITV(0); SCHEDB(); MFMA_CHUNK(3, hB);                                    \
    _Pragma("unroll")                                                         \
    for (int nt = 0; nt < 2; ++nt) {                                          \
      const float cv = nt ? cv1 : cv0;                                        \
      unsigned lo = 0, hi = 0;                                                \
      float hv3 = 0.f;                                                        \
      _Pragma("unroll")                                                       \
      for (int r = 0; r < 4; ++r) {                                           \
        float2 pI = Bp[ 0 + cB + r];                                          \
        float2 pF = Bp[32 + cB + r];                                          \
        float2 pG = Bp[64 + cB + r];                                          \
        float2 pO = Bp[96 + cB + r];                                          \
        float gi = acc[0][nt][r] + pI.x * cv + pI.y;                          \
        float gf = acc[1][nt][r] + pF.x * cv + pF.y;                          \
        float gg = acc[2][nt][r] + pG.x * cv + pG.y;                          \
        float go = acc[3][nt][r] + pO.x * cv + pO.y;                          \
        float ncc = sigm(gf) * cc[nt][r] + sigm(gi) * tanh_(gg);              \
        cc[nt][r] = ncc;                                                      \
        float hval = sigm(go) * tanh_(ncc);                                   \
        unsigned hb = bf16_rne(hval);                                         \
        if (r == 0) lo = hb;                                                  \
        if (r == 1) lo |= hb << 16;                                           \
        if (r == 2) hi = hb;                                                  \
        if (r == 3) { hi |= hb << 16; hv3 = hval; }                           \
      }                                                                       \
      unsigned long long pack =                                               \
          (unsigned long long)lo | ((unsigned long long)hi << 32);            \
      QSTOREX(nxtB + (nt ? soff1 : soff0), pack, SC);                         \
      if (jt == 15 && u == 1 && q == 3)                                       \
        ys[t * (NBR * BATCH) + n * BATCH + (nt ? gb1 : gb0)] = hv3;           \
    }                                                                         \
    if (t == TLEN - 1) break;                                                 \
    WAITV(0);                                                                 \
    const unsigned tgt = (unsigned)(t + 1);                                   \
    if (FM) {                                                                 \
      __syncthreads();             /* all 4 waves' h stores vmcnt-acked */    \
      if (w == 0) {                                                           \
        if (lane == 0) { AUMAX_NR(myflag, tgt, "");                           \
                         AUMAX_NR(myflag, tgt, "sc1"); }                      \
        int spins = 0;                                                        \
        for (;;) {                                                            \
          unsigned fv = 0xFFFFFFFFu;                                          \
          if (lane < 16) {                                                    \
            if (spins < 256) { AUMAX_RET(fv, ppoll, 0u, "sc0"); }             \
            else             { AUMAX_RET(fv, ppoll, 0u, "sc0 sc1"); }         \
          }                                                                   \
          WAITV(0); SCHEDB();                                                 \
          if (__all((int)(fv >= tgt))) break;                                 \
          ++spins; __builtin_amdgcn_s_sleep(1);                               \
        }                                                                     \
        if (lane == 0) sflag = tgt;                                           \
      } else {                                                                \
        while (*((volatile unsigned*)&sflag) < tgt)                           \
          __builtin_amdgcn_s_sleep(1);                                        \
      }                                                                       \
      INVL1(); WAITV(0);           /* L1 clean BEFORE next step's h loads */  \
    } else {                                                                  \
      if (lane == 0) DSTOREX(myflag, tgt, "sc0 sc1");                         \
      for (;;) {                                                              \
        unsigned f0v;                                                         \
        DLOADX(f0v, pf0, "sc0 sc1");                                          \
        WAITV(0); SCHEDB();                                                   \
        if (__all((int)(f0v >= tgt))) break;                                  \
        __builtin_amdgcn_s_sleep(1);                                          \
      }                                                                       \
    }                                                                         \
    char* tsw = curB; curB = nxtB; nxtB = tsw;                                \
  }

__global__ __launch_bounds__(256, 1) void lstm_main(
    const float* __restrict__ c_in,   // (128,256)
    const float* __restrict__ Wih,    // (8,2048)
    const float* __restrict__ Whh,    // (8,2048,512)
    const float* __restrict__ b_ih,   // (8,2048)
    const float* __restrict__ b_hh,   // (8,2048)
    char* __restrict__ hImp,          // 2MB impure ping+pong, pre-zeroed ping
    char* __restrict__ hPure,         // 2MB: 8 XCD regions x (128KB ping + 128KB pong)
    float* __restrict__ ys,           // (256,8,128)
    unsigned int* __restrict__ iflags,// 8x128 impure per-wave flags, pre-zeroed
    unsigned int* __restrict__ pflags,// 8 XCD x 32 blocks x 16 u32 (64B-padded slots)
    unsigned int* __restrict__ vx,    // 256 tagged XCC slots, pre-zeroed
    unsigned int* __restrict__ vdict, // 8 verdicts, pre-zeroed
    unsigned int* __restrict__ ibar)  // 8x32 init-barrier slots, pre-zeroed
{
  __shared__ float2 Bp[128];    // {Wih, b_ih+b_hh} per slice gate-row
  __shared__ unsigned sflag;    // monotone intra-block release sentinel

  const int tid  = threadIdx.x;
  const int lane = tid & 63;
  const int w    = tid >> 6;
  const int ln15 = lane & 15;
  const int q    = lane >> 4;
  const int q4   = q * 4;
  const int n    = blockIdx.x & 7;    // branch
  const int m    = blockIdx.x >> 3;   // 0..31
  const int jt   = m & 15;            // hidden-col tile (32 cols)
  const int bt   = m >> 4;            // batch half (64 rows)
  const int j0   = jt << 5;
  const int bh   = w >> 1;            // wave batch sub-half (32 rows)
  const int u    = w & 1;             // wave col half (16 cols)
  const int cB   = u * 16 + q4;       // col within the 32-col slice

  unsigned xcc_raw;
  asm volatile("s_getreg_b32 %0, hwreg(HW_REG_XCC_ID)" : "=s"(xcc_raw));
  const unsigned xcc = xcc_raw & 0xFu;
  if (tid == 0) { sflag = 0; DSTOREX(&vx[blockIdx.x], 0xA5000000u | xcc, "sc0 sc1"); }

  // ---- load my W slice -> 256 VGPRs (bf16-packed), once ----
  // Frag (tp,ks): 8 bf16 = Whh[gcol = n*2048+tp*512+j0+u*16+ln15][ks*32+q*8 ..+8]
  uint4 wreg[64];
#pragma unroll
  for (int tp = 0; tp < 4; ++tp)
#pragma unroll
    for (int ks = 0; ks < 16; ++ks) {
      const float* src = Whh +
          (size_t)(n * 2048 + tp * 512 + j0 + u * 16 + ln15) * 512 + ks * 32 + q * 8;
      float4 f0 = *(const float4*)(src);
      float4 f1 = *(const float4*)(src + 4);
      uint4 v;
      v.x = (unsigned)bf16_rne(f0.x) | ((unsigned)bf16_rne(f0.y) << 16);
      v.y = (unsigned)bf16_rne(f0.z) | ((unsigned)bf16_rne(f0.w) << 16);
      v.z = (unsigned)bf16_rne(f1.x) | ((unsigned)bf16_rne(f1.y) << 16);
      v.w = (unsigned)bf16_rne(f1.z) | ((unsigned)bf16_rne(f1.w) << 16);
      wreg[tp * 16 + ks] = v;
    }
  if (tid < 128) {
    int g = n * 2048 + (tid >> 5) * 512 + j0 + (tid & 31);
    Bp[tid] = make_float2(Wih[g], b_ih[g] + b_hh[g]);
  }

  // ---- leader (m==0, wave 0): bounded purity check, publish verdict ----
  if (m == 0 && w == 0) {
    const unsigned ref = 0xA5000000u | xcc;
    unsigned v0 = 0, v1 = 0, v2 = 0, v3 = 0;
    int ok = 0;
    for (int it = 0; it < 16384; ++it) {
      DLOADX(v0, &vx[lane],       "sc0 sc1");
      DLOADX(v1, &vx[lane + 64],  "sc0 sc1");
      DLOADX(v2, &vx[lane + 128], "sc0 sc1");
      DLOADX(v3, &vx[lane + 192], "sc0 sc1");
      WAITV(0);
      if (__all((int)(((v0 & 0xFF000000u) == 0xA5000000u) &&
                      ((v1 & 0xFF000000u) == 0xA5000000u) &&
                      ((v2 & 0xFF000000u) == 0xA5000000u) &&
                      ((v3 & 0xFF000000u) == 0xA5000000u)))) { ok = 1; break; }
      __builtin_amdgcn_s_sleep(1);
    }
    unsigned verdict = 0;
    if (ok) {
      const bool mine = ((lane & 7) == n);
      int uni = __all((int)(!mine || (v0 == ref && v1 == ref && v2 == ref && v3 == ref)));
      int oth = __all((int)( mine || (v0 != ref && v1 != ref && v2 != ref && v3 != ref)));
      verdict = (uni && oth && (xcc < 8u)) ? 1u : 0u;
    }
    if (lane == 0)
      DSTOREX(&vdict[n], 0xB5000000u | (verdict << 8) | xcc, "sc0 sc1");
  }

  unsigned vd;
  for (;;) {
    DLOADX(vd, &vdict[n], "sc0 sc1");
    WAITV(0);
    if ((vd & 0xFF000000u) == 0xB5000000u) break;
    __builtin_amdgcn_s_sleep(2);
  }
  const int pure   = (int)((vd >> 8) & 1u);
  const unsigned x = vd & 0xFu;

  const int gb0 = bt * 64 + bh * 32 + ln15;     // my batch rows (global 0..127)
  const int gb1 = gb0 + 16;
  const size_t hoff0 = (size_t)gb0 * 1024 + (size_t)q * 16;
  const size_t hoff1 = (size_t)gb1 * 1024 + (size_t)q * 16;
  const int col0 = j0 + u * 16 + q4;
  const size_t soff0 = (size_t)gb0 * 1024 + (size_t)col0 * 2;
  const size_t soff1 = (size_t)gb1 * 1024 + (size_t)col0 * 2;
  const float* c0p = c_in + (size_t)gb0 * 256;
  const float* c1p = c_in + (size_t)gb1 * 256;

  float cc[2][4];
#pragma unroll
  for (int a = 0; a < 2; ++a)
#pragma unroll
    for (int r = 0; r < 4; ++r) cc[a][r] = 0.0f;

  char *curB, *nxtB;
  unsigned int *flagB, *myflag;
  const unsigned int *ppoll, *pf0;
  if (pure) {
    curB = hPure + (size_t)x * 262144; nxtB = curB + 131072;
    flagB  = pflags + x * 512;                     // 32 slots x 16 u32 (64B stride)
    myflag = flagB + m * 16;
    ppoll  = flagB + (bt * 16 + (lane & 15)) * 16; // 16 same-batch-half producers
    pf0    = flagB;                                // unused
  } else {
    curB = hImp + (size_t)n * 131072; nxtB = curB + (size_t)NBR * 131072;
    flagB  = iflags + n * 128;
    myflag = flagB + m * 4 + w;                    // per-wave flag
    ppoll  = flagB;                                // unused
    pf0    = flagB + bt * 64 + lane;               // 64 same-batch-half wave flags
  }

  __syncthreads();   // Bp + sflag ready; every wave has the verdict

  if (pure) {
    // scrub my 1/32 of region[x] to 0 (stale dirty lines live only in THIS L2)
    char* rp = hPure + (size_t)x * 262144 + (size_t)m * 8192;
    for (int i = tid; i < 1024; i += 256)
      QSTOREXO(rp + (size_t)i * 8, 0ull, "0", "sc0");
    // scrub my flag line: L2 first (dirty-0), THEN MALL (eviction-safe order)
    if (tid == 0) {
      DSTOREX(myflag, 0u, "sc0");
      WAITV(0);
      DSTOREX(myflag, 0u, "sc0 sc1");
    }
    WAITV(0);
    __syncthreads();
    if (tid == 0) DSTOREX(&ibar[x * 32 + m], 1u, "sc0 sc1");
    for (;;) {
      unsigned iv;
      DLOADX(iv, &ibar[x * 32 + (lane & 31)], "sc0 sc1");
      WAITV(0);
      if (__all((int)(iv >= 1u))) break;
      __builtin_amdgcn_s_sleep(2);
    }
    INVL1(); WAITV(0);
    STEP_LOOP("", 1)
  } else {
    STEP_LOOP("sc0 sc1", 0)
  }
}

// out[b,j] = sum_t (sum_n ys[t,n,b] * x[n,b,t]) * Wl[j,t] + bl[j]
__global__ __launch_bounds__(256) void finalize_k(
    const float* __restrict__ ys, const float* __restrict__ x,
    const float* __restrict__ Wl, const float* __restrict__ bl,
    float* __restrict__ out)
{
  int b = blockIdx.x;
  int tid = threadIdx.x;  // = t
  __shared__ float r[256];
  float acc = 0.f;
#pragma unroll
  for (int n = 0; n < NBR; ++n)
    acc += ys[tid * (NBR * BATCH) + n * BATCH + b] * x[(n * BATCH + b) * 256 + tid];
  r[tid] = acc;
  __syncthreads();
  int wv = tid >> 6, ln = tid & 63;
#pragma unroll
  for (int jj = 0; jj < 2; ++jj) {
    int j = wv * 2 + jj;
    float p = 0.f;
#pragma unroll
    for (int t2 = ln; t2 < 256; t2 += 64) p += r[t2] * Wl[j * 256 + t2];
#pragma unroll
    for (int s = 32; s > 0; s >>= 1) p += __shfl_down(p, s, 64);
    if (ln == 0) out[b * NBR + j] = p + bl[j];
  }
}

extern "C" void kernel_launch(void* const* d_in, const int* in_sizes, int n_in,
                              void* d_out, int out_size, void* d_ws, size_t ws_size,
                              hipStream_t stream) {
  const float* x    = (const float*)d_in[0];
  const float* c    = (const float*)d_in[1];
  const float* Wih  = (const float*)d_in[2];
  const float* Whh  = (const float*)d_in[3];
  const float* b_ih = (const float*)d_in[4];
  const float* b_hh = (const float*)d_in[5];
  // d_in[6] = hn0 (zeros; impure ping memset, pure regions scrubbed in-kernel)
  const float* Wl   = (const float*)d_in[7];
  const float* bl   = (const float*)d_in[8];
  float* out = (float*)d_out;

  char* ws = (char*)d_ws;
  char*  hImp  = ws;                                   // 2MB
  char*  hPure = ws + (2u << 20);                      // 2MB (8 x 256KB, XCD-indexed)
  float* ys    = (float*)(ws + (4u << 20));            // 1MB
  unsigned int* ctrl   = (unsigned int*)(ws + (5u << 20));
  unsigned int* iflags = ctrl;                         // 1024 u32
  unsigned int* pflags = ctrl + 1024;                  // 4096 u32 (8x32x16)
  unsigned int* vx     = ctrl + 5120;                  // 256 u32
  unsigned int* vdict  = ctrl + 5376;                  // 8 u32
  unsigned int* ibar   = ctrl + 5384;                  // 256 u32

  // ws re-poisoned (0xAA) before every timed launch: re-init every call.
  (void)hipMemsetAsync(hImp, 0, 1u << 20, stream);     // impure h(t=0) = 0
  (void)hipMemsetAsync(ctrl, 0, 5640u * sizeof(unsigned int), stream);

  lstm_main<<<256, 256, 0, stream>>>(c, Wih, Whh, b_ih, b_hh, hImp, hPure, ys,
                                     iflags, pflags, vx, vdict, ibar);
  finalize_k<<<BATCH, 256, 0, stream>>>(ys, x, Wl, bl, out);
}

// Round 3
// 1677.929 us; speedup vs baseline: 1.0950x; 1.0950x over previous
//
#include <hip/hip_runtime.h>

// 8 independent LSTMs (HID=512, input=1 scalar/step) x T=256, batch 128, then a
// tiny (B,T)->(B,8) projection.
//
// Round 12: LDS W with frag-major (conflict-free) layout + 2x-reuse wave shape.
//  r11 post-mortem: full W-in-registers spilled (VGPR capped 256, scratch
//  round-trips: FETCH +48MB / WRITE +88MB) -> regressed. But LDS_BANK_CONFLICT
//  went to 0, confirming the LDS level was the r10 overhead.
//  r12 = r10 structure + two fixes:
//   - Wave shape 2x2 (from r11): wave = 4 gate-tiles x 16 cols x 32 batch
//     (2 batch frags). Each W frag read once feeds 2 MFMAs: 64 ds_read_b128
//     per wave per step (r10: 128).
//   - Frag-major LDS layout: slot = tile*1024 + ks*64 + q*16 + ln15. Every
//     ds_read_b128 hits 1024 CONTIGUOUS bytes (64 consecutive uint4) -> zero
//     bank conflicts; staging writes are dest-linear -> also conflict-free.
//   - h loads: r11's rolling 2-buffer vmcnt ladder (proven numerics).
//  Exchange protocol identical to r10 (atomic flags at L2 + sc1 escrow, LDS
//  sentinel, INVL1 before h loads; impure fallback = r3 MALL protocol).

#define NBR   8
#define BATCH 128
#define HIDN  512
#define TLEN  256

typedef __attribute__((ext_vector_type(8))) short bf16x8;
typedef __attribute__((ext_vector_type(4))) float f32x4;

__device__ __forceinline__ unsigned short bf16_rne(float f) {
  unsigned int u = __float_as_uint(f);
  u += 0x7FFFu + ((u >> 16) & 1u);
  return (unsigned short)(u >> 16);
}

__device__ __forceinline__ float sigm(float x) {
  return __builtin_amdgcn_rcpf(1.0f + __expf(-x));
}
__device__ __forceinline__ float tanh_(float x) {
  float ax = fabsf(x);
  float e  = __expf(-2.0f * ax);
  float t  = (1.0f - e) * __builtin_amdgcn_rcpf(1.0f + e);
  return copysignf(t, x);
}

#define HLOADX(d, p, OFF, SC) \
  asm volatile("global_load_dwordx4 %0, %1, off offset:" OFF " " SC \
               : "=v"(d) : "v"(p))
#define DLOADX(d, p, SC) \
  asm volatile("global_load_dword %0, %1, off " SC : "=v"(d) : "v"(p))
#define DLOADF(d, p, SC) \
  asm volatile("global_load_dword %0, %1, off " SC : "=v"(d) : "v"(p))
#define QSTOREX(p, v, SC) \
  asm volatile("global_store_dwordx2 %0, %1, off " SC \
               :: "v"(p), "v"(v) : "memory")
#define QSTOREXO(p, v, OFF, SC) \
  asm volatile("global_store_dwordx2 %0, %1, off offset:" OFF " " SC \
               :: "v"(p), "v"(v) : "memory")
#define DSTOREX(p, v, SC) \
  asm volatile("global_store_dword %0, %1, off " SC \
               :: "v"(p), "v"(v) : "memory")
#define WAITV(N) asm volatile("s_waitcnt vmcnt(" #N ")" ::: "memory")
#define INVL1() asm volatile("buffer_inv sc0" ::: "memory")
#define SCHEDB() __builtin_amdgcn_sched_barrier(0)
// L2-executed atomics: cannot be served stale by L1. sc0 on the RET form is
// required (return-old); plain NR form executes at L2, sc1 form at MALL.
#define AUMAX_NR(p, v, SC) \
  asm volatile("global_atomic_umax %0, %1, off " SC :: "v"(p), "v"(v) : "memory")
#define AUMAX_RET(d, p, v, SC) \
  asm volatile("global_atomic_umax %0, %1, %2, off " SC \
               : "=v"(d) : "v"(p), "v"(v) : "memory")

// 8 x 16B: rows gb0/gb1 (via ln15), k-offsets k4*64 within the chunk.
#define CHUNK_LOAD(BUF, P0, P1, SC) do {      \
    HLOADX((BUF)[0], (P0), "0",   SC);        \
    HLOADX((BUF)[1], (P1), "0",   SC);        \
    HLOADX((BUF)[2], (P0), "64",  SC);        \
    HLOADX((BUF)[3], (P1), "64",  SC);        \
    HLOADX((BUF)[4], (P0), "128", SC);        \
    HLOADX((BUF)[5], (P1), "128", SC);        \
    HLOADX((BUF)[6], (P0), "192", SC);        \
    HLOADX((BUF)[7], (P1), "192", SC);        \
  } while (0)

// 4 ksteps x 4 gates x 2 batch-frags; W from LDS (frag-major, conflict-free:
// each read = 64 consecutive uint4), each frag feeds 2 MFMAs.
#define MFMA_CHUNK(C, H) do {                                                 \
    _Pragma("unroll")                                                         \
    for (int k4 = 0; k4 < 4; ++k4) {                                          \
      _Pragma("unroll")                                                       \
      for (int tp = 0; tp < 4; ++tp) {                                        \
        bf16x8 wf = __builtin_bit_cast(bf16x8,                                \
            Wlds[tp * 2048 + wb0 + (4 * (C) + k4) * 64]);                     \
        acc[tp][0] = __builtin_amdgcn_mfma_f32_16x16x32_bf16(                 \
            wf, __builtin_bit_cast(bf16x8, (H)[2 * k4 + 0]), acc[tp][0], 0, 0, 0); \
        acc[tp][1] = __builtin_amdgcn_mfma_f32_16x16x32_bf16(                 \
            wf, __builtin_bit_cast(bf16x8, (H)[2 * k4 + 1]), acc[tp][1], 0, 0, 0); \
      }                                                                       \
    }                                                                         \
  } while (0)

// FM==1: pure (plain h exchange in local L2, atomic flags, LDS sentinel).
// FM==0: r3 MALL protocol (sc0 sc1 everywhere).
#define STEP_LOOP(SC, FM)                                                     \
  for (int t = 0; t < TLEN; ++t) {                                            \
    f32x4 acc[4][2];                                                          \
    _Pragma("unroll")                                                         \
    for (int tp = 0; tp < 4; ++tp)                                            \
      { acc[tp][0] = (f32x4){0.f,0.f,0.f,0.f}; acc[tp][1] = (f32x4){0.f,0.f,0.f,0.f}; } \
    const char* pc0 = curB + hoff0;                                           \
    const char* pc1 = curB + hoff1;                                           \
    uint4 hA[8], hB[8];                                                       \
    float cv0, cv1;                                                           \
    DLOADF(cv0, c0p + t, "");                                                 \
    DLOADF(cv1, c1p + t, "");                                                 \
    CHUNK_LOAD(hA, pc0,       pc1,       SC);                                 \
    CHUNK_LOAD(hB, pc0 + 256, pc1 + 256, SC);                                 \
    WAITV(8); SCHEDB(); MFMA_CHUNK(0, hA);                                    \
    CHUNK_LOAD(hA, pc0 + 512, pc1 + 512, SC);                                 \
    WAITV(8); SCHEDB(); MFMA_CHUNK(1, hB);                                    \
    CHUNK_LOAD(hB, pc0 + 768, pc1 + 768, SC);                                 \
    WAITV(8); SCHEDB(); MFMA_CHUNK(2, hA);                                    \
    WAITV(0); SCHEDB(); MFMA_CHUNK(3, hB);                                    \
    _Pragma("unroll")                                                         \
    for (int nt = 0; nt < 2; ++nt) {                                          \
      const float cv = nt ? cv1 : cv0;                                        \
      unsigned lo = 0, hi = 0;                                                \
      float hv3 = 0.f;                                                        \
      _Pragma("unroll")                                                       \
      for (int r = 0; r < 4; ++r) {                                           \
        float2 pI = Bp[ 0 + cB + r];                                          \
        float2 pF = Bp[32 + cB + r];                                          \
        float2 pG = Bp[64 + cB + r];                                          \
        float2 pO = Bp[96 + cB + r];                                          \
        float gi = acc[0][nt][r] + pI.x * cv + pI.y;                          \
        float gf = acc[1][nt][r] + pF.x * cv + pF.y;                          \
        float gg = acc[2][nt][r] + pG.x * cv + pG.y;                          \
        float go = acc[3][nt][r] + pO.x * cv + pO.y;                          \
        float ncc = sigm(gf) * cc[nt][r] + sigm(gi) * tanh_(gg);              \
        cc[nt][r] = ncc;                                                      \
        float hval = sigm(go) * tanh_(ncc);                                   \
        unsigned hb = bf16_rne(hval);                                         \
        if (r == 0) lo = hb;                                                  \
        if (r == 1) lo |= hb << 16;                                           \
        if (r == 2) hi = hb;                                                  \
        if (r == 3) { hi |= hb << 16; hv3 = hval; }                           \
      }                                                                       \
      unsigned long long pack =                                               \
          (unsigned long long)lo | ((unsigned long long)hi << 32);            \
      QSTOREX(nxtB + (nt ? soff1 : soff0), pack, SC);                         \
      if (jt == 15 && u == 1 && q == 3)                                       \
        ys[t * (NBR * BATCH) + n * BATCH + (nt ? gb1 : gb0)] = hv3;           \
    }                                                                         \
    if (t == TLEN - 1) break;                                                 \
    WAITV(0);                                                                 \
    const unsigned tgt = (unsigned)(t + 1);                                   \
    if (FM) {                                                                 \
      __syncthreads();             /* all 4 waves' h stores vmcnt-acked */    \
      if (w == 0) {                                                           \
        if (lane == 0) { AUMAX_NR(myflag, tgt, "");                           \
                         AUMAX_NR(myflag, tgt, "sc1"); }                      \
        int spins = 0;                                                        \
        for (;;) {                                                            \
          unsigned fv = 0xFFFFFFFFu;                                          \
          if (lane < 16) {                                                    \
            if (spins < 256) { AUMAX_RET(fv, ppoll, 0u, "sc0"); }             \
            else             { AUMAX_RET(fv, ppoll, 0u, "sc0 sc1"); }         \
          }                                                                   \
          WAITV(0); SCHEDB();                                                 \
          if (__all((int)(fv >= tgt))) break;                                 \
          ++spins; __builtin_amdgcn_s_sleep(1);                               \
        }                                                                     \
        if (lane == 0) sflag = tgt;                                           \
      } else {                                                                \
        while (*((volatile unsigned*)&sflag) < tgt)                           \
          __builtin_amdgcn_s_sleep(1);                                        \
      }                                                                       \
      INVL1(); WAITV(0);           /* L1 clean BEFORE next step's h loads */  \
    } else {                                                                  \
      if (lane == 0) DSTOREX(myflag, tgt, "sc0 sc1");                         \
      for (;;) {                                                              \
        unsigned f0v;                                                         \
        DLOADX(f0v, pf0, "sc0 sc1");                                          \
        WAITV(0); SCHEDB();                                                   \
        if (__all((int)(f0v >= tgt))) break;                                  \
        __builtin_amdgcn_s_sleep(1);                                          \
      }                                                                       \
    }                                                                         \
    char* tsw = curB; curB = nxtB; nxtB = tsw;                                \
  }

__global__ __launch_bounds__(256, 1) void lstm_main(
    const float* __restrict__ c_in,   // (128,256)
    const float* __restrict__ Wih,    // (8,2048)
    const float* __restrict__ Whh,    // (8,2048,512)
    const float* __restrict__ b_ih,   // (8,2048)
    const float* __restrict__ b_hh,   // (8,2048)
    char* __restrict__ hImp,          // 2MB impure ping+pong, pre-zeroed ping
    char* __restrict__ hPure,         // 2MB: 8 XCD regions x (128KB ping + 128KB pong)
    float* __restrict__ ys,           // (256,8,128)
    unsigned int* __restrict__ iflags,// 8x128 impure per-wave flags, pre-zeroed
    unsigned int* __restrict__ pflags,// 8 XCD x 32 blocks x 16 u32 (64B-padded slots)
    unsigned int* __restrict__ vx,    // 256 tagged XCC slots, pre-zeroed
    unsigned int* __restrict__ vdict, // 8 verdicts, pre-zeroed
    unsigned int* __restrict__ ibar)  // 8x32 init-barrier slots, pre-zeroed
{
  // Frag-major W: slot = tile*1024 + ks*64 + q*16 + ln15  (tile = tp*2 + u).
  // Each ds_read_b128 (fixed tile,ks) touches 64 CONSECUTIVE uint4 slots.
  __shared__ uint4 Wlds[8192];  // 128KB
  __shared__ float2 Bp[128];    // {Wih, b_ih+b_hh} per slice gate-row
  __shared__ unsigned sflag;    // monotone intra-block release sentinel

  const int tid  = threadIdx.x;
  const int lane = tid & 63;
  const int w    = tid >> 6;
  const int ln15 = lane & 15;
  const int q    = lane >> 4;
  const int q4   = q * 4;
  const int n    = blockIdx.x & 7;    // branch
  const int m    = blockIdx.x >> 3;   // 0..31
  const int jt   = m & 15;            // hidden-col tile (32 cols)
  const int bt   = m >> 4;            // batch half (64 rows)
  const int j0   = jt << 5;
  const int bh   = w >> 1;            // wave batch sub-half (32 rows)
  const int u    = w & 1;             // wave col half (16 cols)
  const int cB   = u * 16 + q4;       // col within the 32-col slice
  const int wb0  = u * 1024 + q * 16 + ln15;  // wave's LDS read base (uint4)

  unsigned xcc_raw;
  asm volatile("s_getreg_b32 %0, hwreg(HW_REG_XCC_ID)" : "=s"(xcc_raw));
  const unsigned xcc = xcc_raw & 0xFu;
  if (tid == 0) { sflag = 0; DSTOREX(&vx[blockIdx.x], 0xA5000000u | xcc, "sc0 sc1"); }

  // ---- stage Whh slice -> LDS bf16, frag-major, dest-linear (once) ----
  for (int idx = tid; idx < 8192; idx += 256) {
    int ln   = idx & 15;          // wcol within 16-col tile
    int q_   = (idx >> 4) & 3;    // k quarter (8 floats)
    int ks_  = (idx >> 6) & 15;   // kstep (32 floats)
    int tile = idx >> 10;         // 0..7 = tp*2 + u
    int tp   = tile >> 1;
    int uu   = tile & 1;
    const float* src = Whh +
        (size_t)(n * 2048 + tp * 512 + j0 + uu * 16 + ln) * 512 + ks_ * 32 + q_ * 8;
    float4 f0 = *(const float4*)(src);
    float4 f1 = *(const float4*)(src + 4);
    uint4 v;
    v.x = (unsigned)bf16_rne(f0.x) | ((unsigned)bf16_rne(f0.y) << 16);
    v.y = (unsigned)bf16_rne(f0.z) | ((unsigned)bf16_rne(f0.w) << 16);
    v.z = (unsigned)bf16_rne(f1.x) | ((unsigned)bf16_rne(f1.y) << 16);
    v.w = (unsigned)bf16_rne(f1.z) | ((unsigned)bf16_rne(f1.w) << 16);
    Wlds[idx] = v;
  }
  if (tid < 128) {
    int g = n * 2048 + (tid >> 5) * 512 + j0 + (tid & 31);
    Bp[tid] = make_float2(Wih[g], b_ih[g] + b_hh[g]);
  }

  // ---- leader (m==0, wave 0): bounded purity check, publish verdict ----
  if (m == 0 && w == 0) {
    const unsigned ref = 0xA5000000u | xcc;
    unsigned v0 = 0, v1 = 0, v2 = 0, v3 = 0;
    int ok = 0;
    for (int it = 0; it < 16384; ++it) {
      DLOADX(v0, &vx[lane],       "sc0 sc1");
      DLOADX(v1, &vx[lane + 64],  "sc0 sc1");
      DLOADX(v2, &vx[lane + 128], "sc0 sc1");
      DLOADX(v3, &vx[lane + 192], "sc0 sc1");
      WAITV(0);
      if (__all((int)(((v0 & 0xFF000000u) == 0xA5000000u) &&
                      ((v1 & 0xFF000000u) == 0xA5000000u) &&
                      ((v2 & 0xFF000000u) == 0xA5000000u) &&
                      ((v3 & 0xFF000000u) == 0xA5000000u)))) { ok = 1; break; }
      __builtin_amdgcn_s_sleep(1);
    }
    unsigned verdict = 0;
    if (ok) {
      const bool mine = ((lane & 7) == n);
      int uni = __all((int)(!mine || (v0 == ref && v1 == ref && v2 == ref && v3 == ref)));
      int oth = __all((int)( mine || (v0 != ref && v1 != ref && v2 != ref && v3 != ref)));
      verdict = (uni && oth && (xcc < 8u)) ? 1u : 0u;
    }
    if (lane == 0)
      DSTOREX(&vdict[n], 0xB5000000u | (verdict << 8) | xcc, "sc0 sc1");
  }

  unsigned vd;
  for (;;) {
    DLOADX(vd, &vdict[n], "sc0 sc1");
    WAITV(0);
    if ((vd & 0xFF000000u) == 0xB5000000u) break;
    __builtin_amdgcn_s_sleep(2);
  }
  const int pure   = (int)((vd >> 8) & 1u);
  const unsigned x = vd & 0xFu;

  const int gb0 = bt * 64 + bh * 32 + ln15;     // my batch rows (global 0..127)
  const int gb1 = gb0 + 16;
  const size_t hoff0 = (size_t)gb0 * 1024 + (size_t)q * 16;
  const size_t hoff1 = (size_t)gb1 * 1024 + (size_t)q * 16;
  const int col0 = j0 + u * 16 + q4;
  const size_t soff0 = (size_t)gb0 * 1024 + (size_t)col0 * 2;
  const size_t soff1 = (size_t)gb1 * 1024 + (size_t)col0 * 2;
  const float* c0p = c_in + (size_t)gb0 * 256;
  const float* c1p = c_in + (size_t)gb1 * 256;

  float cc[2][4];
#pragma unroll
  for (int a = 0; a < 2; ++a)
#pragma unroll
    for (int r = 0; r < 4; ++r) cc[a][r] = 0.0f;

  char *curB, *nxtB;
  unsigned int *flagB, *myflag;
  const unsigned int *ppoll, *pf0;
  if (pure) {
    curB = hPure + (size_t)x * 262144; nxtB = curB + 131072;
    flagB  = pflags + x * 512;                     // 32 slots x 16 u32 (64B stride)
    myflag = flagB + m * 16;
    ppoll  = flagB + (bt * 16 + (lane & 15)) * 16; // 16 same-batch-half producers
    pf0    = flagB;                                // unused
  } else {
    curB = hImp + (size_t)n * 131072; nxtB = curB + (size_t)NBR * 131072;
    flagB  = iflags + n * 128;
    myflag = flagB + m * 4 + w;                    // per-wave flag
    ppoll  = flagB;                                // unused
    pf0    = flagB + bt * 64 + lane;               // 64 same-batch-half wave flags
  }

  __syncthreads();   // Wlds + Bp + sflag ready; every wave has the verdict

  if (pure) {
    // scrub my 1/32 of region[x] to 0 (stale dirty lines live only in THIS L2)
    char* rp = hPure + (size_t)x * 262144 + (size_t)m * 8192;
    for (int i = tid; i < 1024; i += 256)
      QSTOREXO(rp + (size_t)i * 8, 0ull, "0", "sc0");
    // scrub my flag line: L2 first (dirty-0), THEN MALL (eviction-safe order)
    if (tid == 0) {
      DSTOREX(myflag, 0u, "sc0");
      WAITV(0);
      DSTOREX(myflag, 0u, "sc0 sc1");
    }
    WAITV(0);
    __syncthreads();
    if (tid == 0) DSTOREX(&ibar[x * 32 + m], 1u, "sc0 sc1");
    for (;;) {
      unsigned iv;
      DLOADX(iv, &ibar[x * 32 + (lane & 31)], "sc0 sc1");
      WAITV(0);
      if (__all((int)(iv >= 1u))) break;
      __builtin_amdgcn_s_sleep(2);
    }
    INVL1(); WAITV(0);
    STEP_LOOP("", 1)
  } else {
    STEP_LOOP("sc0 sc1", 0)
  }
}

// out[b,j] = sum_t (sum_n ys[t,n,b] * x[n,b,t]) * Wl[j,t] + bl[j]
__global__ __launch_bounds__(256) void finalize_k(
    const float* __restrict__ ys, const float* __restrict__ x,
    const float* __restrict__ Wl, const float* __restrict__ bl,
    float* __restrict__ out)
{
  int b = blockIdx.x;
  int tid = threadIdx.x;  // = t
  __shared__ float r[256];
  float acc = 0.f;
#pragma unroll
  for (int n = 0; n < NBR; ++n)
    acc += ys[tid * (NBR * BATCH) + n * BATCH + b] * x[(n * BATCH + b) * 256 + tid];
  r[tid] = acc;
  __syncthreads();
  int wv = tid >> 6, ln = tid & 63;
#pragma unroll
  for (int jj = 0; jj < 2; ++jj) {
    int j = wv * 2 + jj;
    float p = 0.f;
#pragma unroll
    for (int t2 = ln; t2 < 256; t2 += 64) p += r[t2] * Wl[j * 256 + t2];
#pragma unroll
    for (int s = 32; s > 0; s >>= 1) p += __shfl_down(p, s, 64);
    if (ln == 0) out[b * NBR + j] = p + bl[j];
  }
}

extern "C" void kernel_launch(void* const* d_in, const int* in_sizes, int n_in,
                              void* d_out, int out_size, void* d_ws, size_t ws_size,
                              hipStream_t stream) {
  const float* x    = (const float*)d_in[0];
  const float* c    = (const float*)d_in[1];
  const float* Wih  = (const float*)d_in[2];
  const float* Whh  = (const float*)d_in[3];
  const float* b_ih = (const float*)d_in[4];
  const float* b_hh = (const float*)d_in[5];
  // d_in[6] = hn0 (zeros; impure ping memset, pure regions scrubbed in-kernel)
  const float* Wl   = (const float*)d_in[7];
  const float* bl   = (const float*)d_in[8];
  float* out = (float*)d_out;

  char* ws = (char*)d_ws;
  char*  hImp  = ws;                                   // 2MB
  char*  hPure = ws + (2u << 20);                      // 2MB (8 x 256KB, XCD-indexed)
  float* ys    = (float*)(ws + (4u << 20));            // 1MB
  unsigned int* ctrl   = (unsigned int*)(ws + (5u << 20));
  unsigned int* iflags = ctrl;                         // 1024 u32
  unsigned int* pflags = ctrl + 1024;                  // 4096 u32 (8x32x16)
  unsigned int* vx     = ctrl + 5120;                  // 256 u32
  unsigned int* vdict  = ctrl + 5376;                  // 8 u32
  unsigned int* ibar   = ctrl + 5384;                  // 256 u32

  // ws re-poisoned (0xAA) before every timed launch: re-init every call.
  (void)hipMemsetAsync(hImp, 0, 1u << 20, stream);     // impure h(t=0) = 0
  (void)hipMemsetAsync(ctrl, 0, 5640u * sizeof(unsigned int), stream);

  lstm_main<<<256, 256, 0, stream>>>(c, Wih, Whh, b_ih, b_hh, hImp, hPure, ys,
                                     iflags, pflags, vx, vdict, ibar);
  finalize_k<<<BATCH, 256, 0, stream>>>(ys, x, Wl, bl, out);
}

// Round 4
// 1291.741 us; speedup vs baseline: 1.4224x; 1.2990x over previous
//
#include <hip/hip_runtime.h>

// 8 independent LSTMs (HID=512, input=1 scalar/step) x T=256, batch 128, then a
// tiny (B,T)->(B,8) projection.
//
// Round 13: per-wave closed sync groups + frag-major LDS, on the r10 structure.
//  r12 post-mortem: conflicts->0 but SLOWER than r10 (1678 vs 1492): the 2x2
//  wave shape doubled per-block L2 h reads (128KB vs 64KB/step). LDS conflicts
//  were NOT the r10 critical path. Counters say ~70% of each step is stall =
//  the exchange chain (store-ack -> __syncthreads -> leader 16-flag poll ->
//  LDS sentinel -> INVL1: 4-5 serialized round-trips, gated on slowest wave).
//  r13 = r10 geometry (wave = 16 batch rows x 32 cols, 16 h-loads/lane/step,
//  64KB h/block/step, no duplication) + two changes:
//   - PER-WAVE sync: the 16 waves sharing (bt,w) across jt=0..15 form a closed
//     group (readers of my rows == waves I read). Per-wave flags (64B slots);
//     publish after own store-ack; poll own 16 flags with lane<16 atomics.
//     No __syncthreads, no sentinel, no leader in the pure step loop.
//   - Frag-major Wlds (from r12): slot = tt*1024 + ks*64 + q*16 + ln15; every
//     ds_read_b128 reads 1024 contiguous bytes -> zero bank conflicts.
//  Impure fallback = r3 MALL protocol, unchanged (proven).

#define NBR   8
#define BATCH 128
#define HIDN  512
#define TLEN  256

typedef __attribute__((ext_vector_type(8))) short bf16x8;
typedef __attribute__((ext_vector_type(4))) float f32x4;

__device__ __forceinline__ unsigned short bf16_rne(float f) {
  unsigned int u = __float_as_uint(f);
  u += 0x7FFFu + ((u >> 16) & 1u);
  return (unsigned short)(u >> 16);
}

__device__ __forceinline__ float sigm(float x) {
  return __builtin_amdgcn_rcpf(1.0f + __expf(-x));
}
__device__ __forceinline__ float tanh_(float x) {
  float ax = fabsf(x);
  float e  = __expf(-2.0f * ax);
  float t  = (1.0f - e) * __builtin_amdgcn_rcpf(1.0f + e);
  return copysignf(t, x);
}

#define HLOADX(d, p, OFF, SC) \
  asm volatile("global_load_dwordx4 %0, %1, off offset:" OFF " " SC \
               : "=v"(d) : "v"(p))
#define DLOADX(d, p, SC) \
  asm volatile("global_load_dword %0, %1, off " SC : "=v"(d) : "v"(p))
#define DLOADF(d, p, SC) \
  asm volatile("global_load_dword %0, %1, off " SC : "=v"(d) : "v"(p))
#define QSTOREX(p, v, SC) \
  asm volatile("global_store_dwordx2 %0, %1, off " SC \
               :: "v"(p), "v"(v) : "memory")
#define QSTOREXO(p, v, OFF, SC) \
  asm volatile("global_store_dwordx2 %0, %1, off offset:" OFF " " SC \
               :: "v"(p), "v"(v) : "memory")
#define DSTOREX(p, v, SC) \
  asm volatile("global_store_dword %0, %1, off " SC \
               :: "v"(p), "v"(v) : "memory")
#define WAITV(N) asm volatile("s_waitcnt vmcnt(" #N ")" ::: "memory")
#define INVL1() asm volatile("buffer_inv sc0" ::: "memory")
#define SCHEDB() __builtin_amdgcn_sched_barrier(0)
// L2-executed atomics: cannot be served stale by L1. sc0 on the RET form is
// required (return-old); plain NR form executes at L2, sc1 form at MALL.
#define AUMAX_NR(p, v, SC) \
  asm volatile("global_atomic_umax %0, %1, off " SC :: "v"(p), "v"(v) : "memory")
#define AUMAX_RET(d, p, v, SC) \
  asm volatile("global_atomic_umax %0, %1, %2, off " SC \
               : "=v"(d) : "v"(p), "v"(v) : "memory")

// 16 x 16B: row bb, bytes [q*16 + j*64], j = 0..15 (4 chunks of 4 ksteps).
#define LOAD_H(SC) do {                         \
    HLOADX(hvv[0][0], pc, "0",   SC);           \
    HLOADX(hvv[0][1], pc, "64",  SC);           \
    HLOADX(hvv[0][2], pc, "128", SC);           \
    HLOADX(hvv[0][3], pc, "192", SC);           \
    HLOADX(hvv[1][0], pc, "256", SC);           \
    HLOADX(hvv[1][1], pc, "320", SC);           \
    HLOADX(hvv[1][2], pc, "384", SC);           \
    HLOADX(hvv[1][3], pc, "448", SC);           \
    HLOADX(hvv[2][0], pc, "512", SC);           \
    HLOADX(hvv[2][1], pc, "576", SC);           \
    HLOADX(hvv[2][2], pc, "640", SC);           \
    HLOADX(hvv[2][3], pc, "704", SC);           \
    HLOADX(hvv[3][0], pc, "768", SC);           \
    HLOADX(hvv[3][1], pc, "832", SC);           \
    HLOADX(hvv[3][2], pc, "896", SC);           \
    HLOADX(hvv[3][3], pc, "960", SC);           \
  } while (0)

// 8 tiles tt = gate*2 + u (u = col-16-half); acc[tt] over K chunks. W from
// frag-major LDS: index tt*1024 + ks*64 + wb (wb = q*16+ln15) -> each read is
// 64 consecutive uint4 = conflict-free.
#define MFMA_CHUNK(C) do {                                                    \
    _Pragma("unroll")                                                         \
    for (int k4 = 0; k4 < 4; ++k4) {                                          \
      bf16x8 hfrag = __builtin_bit_cast(bf16x8, hvv[C][k4]);                  \
      _Pragma("unroll")                                                       \
      for (int tt = 0; tt < 8; ++tt) {                                        \
        bf16x8 wf = __builtin_bit_cast(bf16x8,                                \
            Wlds[tt * 1024 + (4 * (C) + k4) * 64 + wb]);                      \
        acc[tt] = __builtin_amdgcn_mfma_f32_16x16x32_bf16(                    \
            wf, hfrag, acc[tt], 0, 0, 0);                                     \
      }                                                                       \
    }                                                                         \
  } while (0)

// FM==1: pure (plain h exchange in local L2, per-wave flags, no syncthreads).
// FM==0: r3 MALL protocol (sc0 sc1 everywhere), per-wave flags at MALL.
#define STEP_LOOP(SC, FM)                                                     \
  for (int t = 0; t < TLEN; ++t) {                                            \
    f32x4 acc[8];                                                             \
    _Pragma("unroll")                                                         \
    for (int tt = 0; tt < 8; ++tt) acc[tt] = (f32x4){0.f, 0.f, 0.f, 0.f};     \
    const char* pc = curB + hoff;                                             \
    uint4 hvv[4][4];                                                          \
    float cv;                                                                 \
    DLOADF(cv, c_ptr + t, "");                                                \
    LOAD_H(SC);                                                               \
    WAITV(12); SCHEDB(); MFMA_CHUNK(0);                                       \
    WAITV(8);  SCHEDB(); MFMA_CHUNK(1);                                       \
    WAITV(4);  SCHEDB(); MFMA_CHUNK(2);                                       \
    WAITV(0);  SCHEDB(); MFMA_CHUNK(3);                                       \
    _Pragma("unroll")                                                         \
    for (int u = 0; u < 2; ++u) {                                             \
      unsigned lo = 0, hi = 0;                                                \
      _Pragma("unroll")                                                       \
      for (int r = 0; r < 4; ++r) {                                           \
        float2 pI = Bp[ 0 + u * 16 + q4 + r];                                 \
        float2 pF = Bp[32 + u * 16 + q4 + r];                                 \
        float2 pG = Bp[64 + u * 16 + q4 + r];                                 \
        float2 pO = Bp[96 + u * 16 + q4 + r];                                 \
        float gi = acc[0 + u][r] + pI.x * cv + pI.y;                          \
        float gf = acc[2 + u][r] + pF.x * cv + pF.y;                          \
        float gg = acc[4 + u][r] + pG.x * cv + pG.y;                          \
        float go = acc[6 + u][r] + pO.x * cv + pO.y;                          \
        float ncc = sigm(gf) * cc[u][r] + sigm(gi) * tanh_(gg);               \
        cc[u][r] = ncc;                                                       \
        float hval = sigm(go) * tanh_(ncc);                                   \
        unsigned hb = bf16_rne(hval);                                         \
        if (r == 0) lo = hb;                                                  \
        if (r == 1) lo |= hb << 16;                                           \
        if (r == 2) hi = hb;                                                  \
        if (r == 3) hi |= hb << 16;                                           \
        if (u == 1 && r == 3 && jt == 15 && q == 3)                           \
          ys[t * (NBR * BATCH) + n * BATCH + bb] = hval;                      \
      }                                                                       \
      unsigned long long pack =                                               \
          (unsigned long long)lo | ((unsigned long long)hi << 32);            \
      QSTOREX(nxtB + (u ? soff1 : soff0), pack, SC);                          \
    }                                                                         \
    if (t == TLEN - 1) break;                                                 \
    WAITV(0);                      /* my stores L2-acked */                   \
    const unsigned tgt = (unsigned)(t + 1);                                   \
    if (FM) {                                                                 \
      if (lane == 0) { AUMAX_NR(myflag, tgt, "");                             \
                       AUMAX_NR(myflag, tgt, "sc1"); }                        \
      int spins = 0;                                                          \
      for (;;) {                                                              \
        unsigned fv = 0xFFFFFFFFu;                                            \
        if (lane < 16) {                                                      \
          if (spins < 256) { AUMAX_RET(fv, ppoll, 0u, "sc0"); }               \
          else             { AUMAX_RET(fv, ppoll, 0u, "sc0 sc1"); }           \
        }                                                                     \
        WAITV(0); SCHEDB();                                                   \
        if (__all((int)(fv >= tgt))) break;                                   \
        ++spins; __builtin_amdgcn_s_sleep(1);                                 \
      }                                                                       \
      INVL1(); WAITV(0);           /* L1 clean BEFORE next step's h loads */  \
    } else {                                                                  \
      if (lane == 0) DSTOREX(myflag, tgt, "sc0 sc1");                         \
      for (;;) {                                                              \
        unsigned f0v;                                                         \
        DLOADX(f0v, pf0, "sc0 sc1");                                          \
        WAITV(0); SCHEDB();                                                   \
        if (__all((int)(f0v >= tgt))) break;                                  \
        __builtin_amdgcn_s_sleep(1);                                          \
      }                                                                       \
    }                                                                         \
    char* tsw = curB; curB = nxtB; nxtB = tsw;                                \
  }

__global__ __launch_bounds__(256, 1) void lstm_main(
    const float* __restrict__ c_in,   // (128,256)
    const float* __restrict__ Wih,    // (8,2048)
    const float* __restrict__ Whh,    // (8,2048,512)
    const float* __restrict__ b_ih,   // (8,2048)
    const float* __restrict__ b_hh,   // (8,2048)
    char* __restrict__ hImp,          // 2MB impure ping+pong, pre-zeroed ping
    char* __restrict__ hPure,         // 2MB: 8 XCD regions x (128KB ping + 128KB pong)
    float* __restrict__ ys,           // (256,8,128)
    unsigned int* __restrict__ iflags,// 8x128 impure per-wave flags, pre-zeroed
    unsigned int* __restrict__ pflags,// 8 XCD x 128 wave-slots x 16 u32 (64B pads)
    unsigned int* __restrict__ vx,    // 256 tagged XCC slots, pre-zeroed
    unsigned int* __restrict__ vdict, // 8 verdicts, pre-zeroed
    unsigned int* __restrict__ ibar)  // 8x32 init-barrier slots, pre-zeroed
{
  // Frag-major W: slot = tile*1024 + ks*64 + q*16 + ln15  (tile = gate*2 + u).
  // Each ds_read_b128 (fixed tile,ks) touches 64 CONSECUTIVE uint4 slots.
  __shared__ uint4 Wlds[8192];  // 128KB
  __shared__ float2 Bp[128];    // {Wih, b_ih+b_hh} per slice gate-row
  __shared__ unsigned sflag;    // (unused in pure loop; kept for init zeroing)

  const int tid  = threadIdx.x;
  const int lane = tid & 63;
  const int w    = tid >> 6;
  const int ln15 = lane & 15;
  const int q    = lane >> 4;
  const int q4   = q * 4;
  const int n    = blockIdx.x & 7;    // branch
  const int m    = blockIdx.x >> 3;   // 0..31
  const int jt   = m & 15;            // hidden-col tile (32 cols)
  const int bt   = m >> 4;            // batch half (64 rows)
  const int j0   = jt << 5;
  const int wb   = q * 16 + ln15;     // frag-major LDS read base (uint4)

  unsigned xcc_raw;
  asm volatile("s_getreg_b32 %0, hwreg(HW_REG_XCC_ID)" : "=s"(xcc_raw));
  const unsigned xcc = xcc_raw & 0xFu;
  if (tid == 0) { sflag = 0; DSTOREX(&vx[blockIdx.x], 0xA5000000u | xcc, "sc0 sc1"); }

  // ---- stage Whh slice -> LDS bf16, frag-major, dest-linear (once) ----
  for (int idx = tid; idx < 8192; idx += 256) {
    int ln   = idx & 15;          // wcol within 16-col tile
    int q_   = (idx >> 4) & 3;    // k quarter (8 floats)
    int ks_  = (idx >> 6) & 15;   // kstep (32 floats)
    int tile = idx >> 10;         // 0..7 = gate*2 + u
    int g_   = tile >> 1;
    int uu   = tile & 1;
    const float* src = Whh +
        (size_t)(n * 2048 + g_ * 512 + j0 + uu * 16 + ln) * 512 + ks_ * 32 + q_ * 8;
    float4 f0 = *(const float4*)(src);
    float4 f1 = *(const float4*)(src + 4);
    uint4 v;
    v.x = (unsigned)bf16_rne(f0.x) | ((unsigned)bf16_rne(f0.y) << 16);
    v.y = (unsigned)bf16_rne(f0.z) | ((unsigned)bf16_rne(f0.w) << 16);
    v.z = (unsigned)bf16_rne(f1.x) | ((unsigned)bf16_rne(f1.y) << 16);
    v.w = (unsigned)bf16_rne(f1.z) | ((unsigned)bf16_rne(f1.w) << 16);
    Wlds[idx] = v;
  }
  if (tid < 128) {
    int g = n * 2048 + (tid >> 5) * 512 + j0 + (tid & 31);
    Bp[tid] = make_float2(Wih[g], b_ih[g] + b_hh[g]);
  }

  // ---- leader (m==0, wave 0): bounded purity check, publish verdict ----
  if (m == 0 && w == 0) {
    const unsigned ref = 0xA5000000u | xcc;
    unsigned v0 = 0, v1 = 0, v2 = 0, v3 = 0;
    int ok = 0;
    for (int it = 0; it < 16384; ++it) {
      DLOADX(v0, &vx[lane],       "sc0 sc1");
      DLOADX(v1, &vx[lane + 64],  "sc0 sc1");
      DLOADX(v2, &vx[lane + 128], "sc0 sc1");
      DLOADX(v3, &vx[lane + 192], "sc0 sc1");
      WAITV(0);
      if (__all((int)(((v0 & 0xFF000000u) == 0xA5000000u) &&
                      ((v1 & 0xFF000000u) == 0xA5000000u) &&
                      ((v2 & 0xFF000000u) == 0xA5000000u) &&
                      ((v3 & 0xFF000000u) == 0xA5000000u)))) { ok = 1; break; }
      __builtin_amdgcn_s_sleep(1);
    }
    unsigned verdict = 0;
    if (ok) {
      const bool mine = ((lane & 7) == n);
      int uni = __all((int)(!mine || (v0 == ref && v1 == ref && v2 == ref && v3 == ref)));
      int oth = __all((int)( mine || (v0 != ref && v1 != ref && v2 != ref && v3 != ref)));
      verdict = (uni && oth && (xcc < 8u)) ? 1u : 0u;
    }
    if (lane == 0)
      DSTOREX(&vdict[n], 0xB5000000u | (verdict << 8) | xcc, "sc0 sc1");
  }

  unsigned vd;
  for (;;) {
    DLOADX(vd, &vdict[n], "sc0 sc1");
    WAITV(0);
    if ((vd & 0xFF000000u) == 0xB5000000u) break;
    __builtin_amdgcn_s_sleep(2);
  }
  const int pure   = (int)((vd >> 8) & 1u);
  const unsigned x = vd & 0xFu;

  const int bb = bt * 64 + w * 16 + ln15;       // my batch row
  const size_t hoff  = (size_t)bb * 1024 + (size_t)q * 16;
  const size_t soff0 = (size_t)bb * 1024 + (size_t)(j0 + q4) * 2;
  const size_t soff1 = soff0 + 32;              // +16 cols
  const float* c_ptr = c_in + (size_t)bb * 256;

  float cc[2][4];
#pragma unroll
  for (int u = 0; u < 2; ++u)
#pragma unroll
    for (int r = 0; r < 4; ++r) cc[u][r] = 0.0f;

  char *curB, *nxtB;
  unsigned int *flagB, *myflag;
  const unsigned int *ppoll, *pf0;
  if (pure) {
    curB = hPure + (size_t)x * 262144; nxtB = curB + 131072;
    flagB  = pflags + x * 2048;                  // 128 wave-slots x 16 u32
    myflag = flagB + ((bt * 4 + w) * 16 + jt) * 16;
    ppoll  = flagB + ((bt * 4 + w) * 16 + (lane & 15)) * 16;  // my 16-wave group
    pf0    = flagB;                              // unused
  } else {
    curB = hImp + (size_t)n * 131072; nxtB = curB + (size_t)NBR * 131072;
    flagB  = iflags + n * 128;
    myflag = flagB + m * 4 + w;                  // per-wave flag
    ppoll  = flagB;                              // unused
    pf0    = flagB + bt * 64 + lane;             // 64 same-batch-half wave flags
  }

  __syncthreads();   // Wlds + Bp ready; every wave has the verdict

  if (pure) {
    // scrub my 1/32 of region[x] to 0 (stale dirty lines live only in THIS L2)
    char* rp = hPure + (size_t)x * 262144 + (size_t)m * 8192;
    for (int i = tid; i < 1024; i += 256)
      QSTOREXO(rp + (size_t)i * 8, 0ull, "0", "sc0");
    // scrub my wave's flag line: L2 first (dirty-0), THEN MALL (eviction-safe)
    if (lane == 0) {
      DSTOREX(myflag, 0u, "sc0");
      WAITV(0);
      DSTOREX(myflag, 0u, "sc0 sc1");
    }
    WAITV(0);
    __syncthreads();
    if (tid == 0) DSTOREX(&ibar[x * 32 + m], 1u, "sc0 sc1");
    for (;;) {
      unsigned iv;
      DLOADX(iv, &ibar[x * 32 + (lane & 31)], "sc0 sc1");
      WAITV(0);
      if (__all((int)(iv >= 1u))) break;
      __builtin_amdgcn_s_sleep(2);
    }
    INVL1(); WAITV(0);
    STEP_LOOP("", 1)
  } else {
    STEP_LOOP("sc0 sc1", 0)
  }
}

// out[b,j] = sum_t (sum_n ys[t,n,b] * x[n,b,t]) * Wl[j,t] + bl[j]
__global__ __launch_bounds__(256) void finalize_k(
    const float* __restrict__ ys, const float* __restrict__ x,
    const float* __restrict__ Wl, const float* __restrict__ bl,
    float* __restrict__ out)
{
  int b = blockIdx.x;
  int tid = threadIdx.x;  // = t
  __shared__ float r[256];
  float acc = 0.f;
#pragma unroll
  for (int n = 0; n < NBR; ++n)
    acc += ys[tid * (NBR * BATCH) + n * BATCH + b] * x[(n * BATCH + b) * 256 + tid];
  r[tid] = acc;
  __syncthreads();
  int wv = tid >> 6, ln = tid & 63;
#pragma unroll
  for (int jj = 0; jj < 2; ++jj) {
    int j = wv * 2 + jj;
    float p = 0.f;
#pragma unroll
    for (int t2 = ln; t2 < 256; t2 += 64) p += r[t2] * Wl[j * 256 + t2];
#pragma unroll
    for (int s = 32; s > 0; s >>= 1) p += __shfl_down(p, s, 64);
    if (ln == 0) out[b * NBR + j] = p + bl[j];
  }
}

extern "C" void kernel_launch(void* const* d_in, const int* in_sizes, int n_in,
                              void* d_out, int out_size, void* d_ws, size_t ws_size,
                              hipStream_t stream) {
  const float* x    = (const float*)d_in[0];
  const float* c    = (const float*)d_in[1];
  const float* Wih  = (const float*)d_in[2];
  const float* Whh  = (const float*)d_in[3];
  const float* b_ih = (const float*)d_in[4];
  const float* b_hh = (const float*)d_in[5];
  // d_in[6] = hn0 (zeros; impure ping memset, pure regions scrubbed in-kernel)
  const float* Wl   = (const float*)d_in[7];
  const float* bl   = (const float*)d_in[8];
  float* out = (float*)d_out;

  char* ws = (char*)d_ws;
  char*  hImp  = ws;                                   // 2MB
  char*  hPure = ws + (2u << 20);                      // 2MB (8 x 256KB, XCD-indexed)
  float* ys    = (float*)(ws + (4u << 20));            // 1MB
  unsigned int* ctrl   = (unsigned int*)(ws + (5u << 20));
  unsigned int* iflags = ctrl;                         // 1024 u32
  unsigned int* pflags = ctrl + 1024;                  // 16384 u32 (8 x 128 x 16)
  unsigned int* vx     = ctrl + 17408;                 // 256 u32
  unsigned int* vdict  = ctrl + 17664;                 // 8 u32
  unsigned int* ibar   = ctrl + 17672;                 // 256 u32

  // ws re-poisoned (0xAA) before every timed launch: re-init every call.
  (void)hipMemsetAsync(hImp, 0, 1u << 20, stream);     // impure h(t=0) = 0
  (void)hipMemsetAsync(ctrl, 0, 17928u * sizeof(unsigned int), stream);

  lstm_main<<<256, 256, 0, stream>>>(c, Wih, Whh, b_ih, b_hh, hImp, hPure, ys,
                                     iflags, pflags, vx, vdict, ibar);
  finalize_k<<<BATCH, 256, 0, stream>>>(ys, x, Wl, bl, out);
}